// Round 8
// baseline (1159.306 us; speedup 1.0000x reference)
//
#include <hip/hip_runtime.h>
#include <hip/hip_fp16.h>
#include <math.h>
#include <float.h>

#define NN 100000
#define NE 1600000

#define SCAN_T 256
#define SCAN_E 1024
#define SCAN_NB ((NN + SCAN_E - 1) / SCAN_E)   // 98

#define NBUCK ((NN + 255) / 256)               // 391 buckets of 256 dsts
#define BCAP  5120                             // mean 4092, sd 64 -> huge margin

// ---------------- fused linear: q,skip fp32; k,v packed fp16 (R6 verbatim) ----------------
template<int IN, int OUT, int NPT, int NWIN>
__global__ __launch_bounds__(256)
void linear_qkvs(const float* __restrict__ x,
                 const float* __restrict__ Wq, const float* __restrict__ bq,
                 const float* __restrict__ Wk, const float* __restrict__ bk,
                 const float* __restrict__ Wv, const float* __restrict__ bv,
                 const float* __restrict__ Ws, const float* __restrict__ bs,
                 float* __restrict__ q, unsigned short* __restrict__ kv,
                 float* __restrict__ outskip) {
    const int t    = threadIdx.x;
    const int lane = t & 63;
    const int wv   = t >> 6;
    const int wid  = blockIdx.y * 4 + wv;        // [0, 4*NWIN)
    const int mat  = wid / NWIN;                 // 0..3 (wave-uniform)
    const int win  = wid % NWIN;
    const int c    = win * 64 + lane;
    const bool act = (c < OUT);
    const int cl   = act ? c : (OUT - 1);

    const float* W = (mat == 0) ? Wq : (mat == 1) ? Wk : (mat == 2) ? Wv : Ws;
    const float* B = (mat == 0) ? bq : (mat == 1) ? bk : (mat == 2) ? bv : bs;

    const int node0 = blockIdx.x * NPT;
    const float* xrow = x + (size_t)node0 * IN;

    float acc[NPT];
    float bias = B[cl];
#pragma unroll
    for (int p = 0; p < NPT; ++p) acc[p] = bias;

    for (int i0 = 0; i0 < IN; i0 += 4) {
        float w0 = W[(size_t)(i0 + 0) * OUT + cl];
        float w1 = W[(size_t)(i0 + 1) * OUT + cl];
        float w2 = W[(size_t)(i0 + 2) * OUT + cl];
        float w3 = W[(size_t)(i0 + 3) * OUT + cl];
#pragma unroll
        for (int p = 0; p < NPT; ++p) {
            float4 xv = *(const float4*)(xrow + p * IN + i0);  // wave-uniform
            acc[p] += xv.x * w0 + xv.y * w1 + xv.z * w2 + xv.w * w3;
        }
    }

    if (mat == 0) {
        if (act) {
#pragma unroll
            for (int p = 0; p < NPT; ++p)
                q[(size_t)(node0 + p) * OUT + c] = acc[p];
        }
    } else if (mat == 3) {
        if (act) {
#pragma unroll
            for (int p = 0; p < NPT; ++p)
                outskip[(size_t)(node0 + p) * OUT + c] = acc[p];
        }
    } else {
        const int base = (mat == 1) ? 0 : OUT;   // k block then v block
#pragma unroll
        for (int p = 0; p < NPT; ++p) {
            float other = __shfl_xor(acc[p], 1); // all lanes participate
            if (act && !(lane & 1)) {
                unsigned lo  = __half_as_ushort(__float2half_rn(acc[p]));
                unsigned hiu = __half_as_ushort(__float2half_rn(other));
                *(unsigned*)(kv + (size_t)(node0 + p) * (2 * OUT) + base + c)
                    = lo | (hiu << 16);
            }
        }
    }
}

// ---------------- CSR build via two-phase bucket sort ----------------
// Phase A: scatter packed (dst_local<<17 | src) into per-(dst>>8) buckets.
// Writes are sequential within each bucket -> L2 absorbs to ~compact traffic.
__global__ __launch_bounds__(256)
void bucket_scatter(const int* __restrict__ ei,
                    int* __restrict__ bucket_cnt,
                    unsigned* __restrict__ bucket_buf) {
    int e = blockIdx.x * 256 + threadIdx.x;
    if (e >= NE) return;
    int src = ei[e];
    int dst = ei[NE + e];
    int b = dst >> 8;
    unsigned pack = ((unsigned)(dst & 255) << 17) | (unsigned)src;
    int p = atomicAdd(&bucket_cnt[b], 1);
    if (p < BCAP) bucket_buf[(size_t)b * BCAP + p] = pack;
}

// Phase B1: per-bucket LDS histogram -> per-dst counts (replaces global hist).
__global__ __launch_bounds__(256)
void bucket_hist(const int* __restrict__ bucket_cnt,
                 const unsigned* __restrict__ bucket_buf,
                 int* __restrict__ counts) {
    __shared__ int h[256];
    const int b = blockIdx.x;
    const int t = threadIdx.x;
    h[t] = 0;
    __syncthreads();
    int cnt = bucket_cnt[b];
    cnt = cnt < BCAP ? cnt : BCAP;
    const unsigned* buf = bucket_buf + (size_t)b * BCAP;
    for (int i = t; i < cnt; i += 256)
        atomicAdd(&h[buf[i] >> 17], 1);
    __syncthreads();
    int d = b * 256 + t;
    if (d < NN) counts[d] = h[t];
}

__global__ __launch_bounds__(SCAN_T)
void scan1(const int* __restrict__ counts, int* __restrict__ offsets,
           int* __restrict__ blocksums) {
    __shared__ int lds[SCAN_T];
    int t = threadIdx.x;
    int base = blockIdx.x * SCAN_E + t * 4;
    int vals[4];
    int s = 0;
#pragma unroll
    for (int j = 0; j < 4; ++j) {
        int idx = base + j;
        vals[j] = (idx < NN) ? counts[idx] : 0;
        s += vals[j];
    }
    lds[t] = s;
    __syncthreads();
    for (int off = 1; off < SCAN_T; off <<= 1) {
        int xx = (t >= off) ? lds[t - off] : 0;
        __syncthreads();
        lds[t] += xx;
        __syncthreads();
    }
    int run = (t > 0) ? lds[t - 1] : 0;
    if (t == SCAN_T - 1) blocksums[blockIdx.x] = lds[t];
#pragma unroll
    for (int j = 0; j < 4; ++j) {
        int idx = base + j;
        if (idx < NN) offsets[idx] = run;
        run += vals[j];
    }
}

__global__ __launch_bounds__(128)
void scan2(int* __restrict__ blocksums) {
    __shared__ int lds[128];
    int t = threadIdx.x;
    lds[t] = (t < SCAN_NB) ? blocksums[t] : 0;
    __syncthreads();
    for (int off = 1; off < 128; off <<= 1) {
        int xx = (t >= off) ? lds[t - off] : 0;
        __syncthreads();
        lds[t] += xx;
        __syncthreads();
    }
    if (t < SCAN_NB) blocksums[t] = (t > 0) ? lds[t - 1] : 0;
}

__global__ __launch_bounds__(256)
void scan3(int* __restrict__ offsets, const int* __restrict__ blocksums) {
    int i = blockIdx.x * blockDim.x + threadIdx.x;
    if (i < NN) offsets[i] = offsets[i] + blocksums[i / SCAN_E];
    if (i == 0) offsets[NN] = NE;
}

// Phase B2: sort each bucket in LDS, write its (contiguous) CSR segment coalesced.
__global__ __launch_bounds__(256)
void csr_write(const int* __restrict__ bucket_cnt,
               const unsigned* __restrict__ bucket_buf,
               const int* __restrict__ offsets,
               int* __restrict__ sorted_src) {
    __shared__ int h[256];
    __shared__ int pre[256];
    __shared__ int posi[256];
    __shared__ unsigned srt[BCAP];
    const int b = blockIdx.x;
    const int t = threadIdx.x;
    h[t] = 0;
    __syncthreads();
    int cnt = bucket_cnt[b];
    cnt = cnt < BCAP ? cnt : BCAP;
    const unsigned* buf = bucket_buf + (size_t)b * BCAP;
    for (int i = t; i < cnt; i += 256)
        atomicAdd(&h[buf[i] >> 17], 1);
    __syncthreads();
    // exclusive prefix over 256 dst_locals
    int v = h[t];
    pre[t] = v;
    __syncthreads();
    for (int off = 1; off < 256; off <<= 1) {
        int xx = (t >= off) ? pre[t - off] : 0;
        __syncthreads();
        pre[t] += xx;
        __syncthreads();
    }
    posi[t] = pre[t] - v;   // exclusive
    __syncthreads();
    for (int i = t; i < cnt; i += 256) {
        unsigned u = buf[i];
        int dl = u >> 17;
        int p = atomicAdd(&posi[dl], 1);
        srt[p] = u & 0x1FFFFu;
    }
    __syncthreads();
    const int base = offsets[b << 8];
    for (int i = t; i < cnt; i += 256)
        sorted_src[base + i] = (int)srt[i];
}

// ---- 16-lane row sum via DPP rotates (VALU pipe, no LDS) ----
__device__ __forceinline__ float row16_sum(float x) {
    int y;
    y = __builtin_amdgcn_update_dpp(0, __float_as_int(x), 0x121, 0xF, 0xF, true); x += __int_as_float(y); // ror:1
    y = __builtin_amdgcn_update_dpp(0, __float_as_int(x), 0x122, 0xF, 0xF, true); x += __int_as_float(y); // ror:2
    y = __builtin_amdgcn_update_dpp(0, __float_as_int(x), 0x124, 0xF, 0xF, true); x += __int_as_float(y); // ror:4
    y = __builtin_amdgcn_update_dpp(0, __float_as_int(x), 0x128, 0xF, 0xF, true); x += __int_as_float(y); // ror:8
    return x;
}

__device__ __forceinline__ float4 h4_to_f4(uint2 w) {
    union { unsigned u; __half2 h; } a, b;
    a.u = w.x; b.u = w.y;
    float2 f0 = __half22float2(a.h);
    float2 f1 = __half22float2(b.h);
    return make_float4(f0.x, f0.y, f1.x, f1.y);
}

// ---------------- fused attention gather (R6 verbatim) ----------------
template<int C, bool RELU>
__global__ __launch_bounds__(256)
void attn_gather(const int* __restrict__ offsets,
                 const int* __restrict__ sorted_src,
                 const float* __restrict__ q,
                 const unsigned short* __restrict__ kv,
                 float* __restrict__ out, float scale) {
    const int wid  = (int)((blockIdx.x * blockDim.x + threadIdx.x) >> 6);
    const int lane = threadIdx.x & 63;
    if (wid >= NN) return;
    const int grp = lane >> 4;
    const int ch  = (lane & 15) * 4;
    constexpr bool P2 = (C > 64);
    const bool hi = P2 && (ch + 64 < C);

    const int beg = offsets[wid], end = offsets[wid + 1];

    float4 qv0 = *(const float4*)(q + (size_t)wid * C + ch);
    float4 qv1 = make_float4(0.f, 0.f, 0.f, 0.f);
    if (hi) qv1 = *(const float4*)(q + (size_t)wid * C + ch + 64);

    float m = -FLT_MAX, l = 0.f;
    float4 a0 = make_float4(0.f, 0.f, 0.f, 0.f);
    float4 a1 = make_float4(0.f, 0.f, 0.f, 0.f);

    int i = beg + grp;
    uint2 kw0 = make_uint2(0, 0), vw0 = kw0, kw1 = kw0, vw1 = kw0;
    if (i < end) {
        const unsigned short* row = kv + (size_t)sorted_src[i] * (2 * C);
        kw0 = *(const uint2*)(row + ch);
        vw0 = *(const uint2*)(row + C + ch);
        if (hi) {
            kw1 = *(const uint2*)(row + 64 + ch);
            vw1 = *(const uint2*)(row + C + 64 + ch);
        }
    }
    while (i < end) {
        int inext = i + 4;
        uint2 nkw0 = make_uint2(0, 0), nvw0 = nkw0, nkw1 = nkw0, nvw1 = nkw0;
        if (inext < end) {
            const unsigned short* row = kv + (size_t)sorted_src[inext] * (2 * C);
            nkw0 = *(const uint2*)(row + ch);
            nvw0 = *(const uint2*)(row + C + ch);
            if (hi) {
                nkw1 = *(const uint2*)(row + 64 + ch);
                nvw1 = *(const uint2*)(row + C + 64 + ch);
            }
        }
        float4 kf0 = h4_to_f4(kw0);
        float4 vf0 = h4_to_f4(vw0);
        float part = qv0.x * kf0.x + qv0.y * kf0.y + qv0.z * kf0.z + qv0.w * kf0.w;
        float4 kf1, vf1;
        if (P2) {
            kf1 = h4_to_f4(kw1);
            vf1 = h4_to_f4(vw1);
            part += qv1.x * kf1.x + qv1.y * kf1.y + qv1.z * kf1.z + qv1.w * kf1.w;
        }
        float s = row16_sum(part) * scale;
        float mn = fmaxf(m, s);
        float al = __expf(m - mn);
        float w  = __expf(s - mn);
        l = l * al + w;
        a0.x = a0.x * al + w * vf0.x; a0.y = a0.y * al + w * vf0.y;
        a0.z = a0.z * al + w * vf0.z; a0.w = a0.w * al + w * vf0.w;
        if (P2) {
            a1.x = a1.x * al + w * vf1.x; a1.y = a1.y * al + w * vf1.y;
            a1.z = a1.z * al + w * vf1.z; a1.w = a1.w * al + w * vf1.w;
        }
        m = mn;
        kw0 = nkw0; vw0 = nvw0; kw1 = nkw1; vw1 = nvw1;
        i = inext;
    }

    // merge the 4 groups: butterfly over lane-xor 16, 32
#pragma unroll
    for (int d = 16; d <= 32; d <<= 1) {
        float mo = __shfl_xor(m, d);
        float lo = __shfl_xor(l, d);
        float4 ao0, ao1;
        ao0.x = __shfl_xor(a0.x, d); ao0.y = __shfl_xor(a0.y, d);
        ao0.z = __shfl_xor(a0.z, d); ao0.w = __shfl_xor(a0.w, d);
        if (P2) {
            ao1.x = __shfl_xor(a1.x, d); ao1.y = __shfl_xor(a1.y, d);
            ao1.z = __shfl_xor(a1.z, d); ao1.w = __shfl_xor(a1.w, d);
        }
        float mn = fmaxf(m, mo);
        float e1 = (l  > 0.f) ? __expf(m  - mn) : 0.f;
        float e2 = (lo > 0.f) ? __expf(mo - mn) : 0.f;
        l = l * e1 + lo * e2;
        a0.x = a0.x * e1 + ao0.x * e2; a0.y = a0.y * e1 + ao0.y * e2;
        a0.z = a0.z * e1 + ao0.z * e2; a0.w = a0.w * e1 + ao0.w * e2;
        if (P2) {
            a1.x = a1.x * e1 + ao1.x * e2; a1.y = a1.y * e1 + ao1.y * e2;
            a1.z = a1.z * e1 + ao1.z * e2; a1.w = a1.w * e1 + ao1.w * e2;
        }
        m = mn;
    }

    if (lane < 16) {
        float inv = (l > 0.f) ? 1.f / l : 0.f;
        size_t o = (size_t)wid * C + ch;
        float4 sk = *(const float4*)(out + o);
        float4 r;
        r.x = sk.x + a0.x * inv; r.y = sk.y + a0.y * inv;
        r.z = sk.z + a0.z * inv; r.w = sk.w + a0.w * inv;
        if (RELU) {
            r.x = fmaxf(r.x, 0.f); r.y = fmaxf(r.y, 0.f);
            r.z = fmaxf(r.z, 0.f); r.w = fmaxf(r.w, 0.f);
        }
        *(float4*)(out + o) = r;
        if (hi) {
            float4 sk1 = *(const float4*)(out + o + 64);
            float4 r1;
            r1.x = sk1.x + a1.x * inv; r1.y = sk1.y + a1.y * inv;
            r1.z = sk1.z + a1.z * inv; r1.w = sk1.w + a1.w * inv;
            if (RELU) {
                r1.x = fmaxf(r1.x, 0.f); r1.y = fmaxf(r1.y, 0.f);
                r1.z = fmaxf(r1.z, 0.f); r1.w = fmaxf(r1.w, 0.f);
            }
            *(float4*)(out + o + 64) = r1;
        }
    }
}

// ---------------- host side ----------------
template<int IN, int OUT, bool RELU>
static void run_layer(const float* xin, const float* const* Wb,
                      const int* offsets, const int* sorted_src,
                      float* q, unsigned short* kv,
                      float* out, hipStream_t stream) {
    constexpr int NPT  = 16;                    // NN = 6250 * 16 exactly
    constexpr int NWIN = (OUT + 63) / 64;
    dim3 gl(NN / NPT, NWIN);
    linear_qkvs<IN, OUT, NPT, NWIN><<<gl, 256, 0, stream>>>(
        xin, Wb[0], Wb[1], Wb[2], Wb[3], Wb[4], Wb[5], Wb[6], Wb[7],
        q, kv, out);

    float scale = 1.0f / sqrtf((float)OUT);
    attn_gather<OUT, RELU><<<(NN + 3) / 4, 256, 0, stream>>>(
        offsets, sorted_src, q, kv, out, scale);
}

extern "C" void kernel_launch(void* const* d_in, const int* in_sizes, int n_in,
                              void* d_out, int out_size, void* d_ws, size_t ws_size,
                              hipStream_t stream) {
    const float* x  = (const float*)d_in[0];
    const int*   ei = (const int*)d_in[1];
    const float* Wb0[8], *Wb1[8], *Wb2[8];
    for (int i = 0; i < 8; ++i) {
        Wb0[i] = (const float*)d_in[2 + i];
        Wb1[i] = (const float*)d_in[10 + i];
        Wb2[i] = (const float*)d_in[18 + i];
    }
    float* out = (float*)d_out;

    char* ws = (char*)d_ws;
    const size_t CMAX = 112;
    size_t off = 0;
    float*          q  = (float*)(ws + off);          off += (size_t)NN * CMAX * 4;
    unsigned short* kv = (unsigned short*)(ws + off); off += (size_t)NN * 2 * CMAX * 2;
    float* h0          = (float*)(ws + off);          off += (size_t)NN * 64 * 4;
    float* h1          = (float*)(ws + off);          off += (size_t)NN * 64 * 4;
    int*   sorted_src  = (int*)(ws + off);            off += (size_t)NE * 4;
    int*   counts      = (int*)(ws + off);            off += (size_t)NN * 4;
    int*   offsets     = (int*)(ws + off);            off += (size_t)(NN + 1) * 4;
    int*   blocksums   = (int*)(ws + off);            off += (size_t)SCAN_NB * 4;
    int*   bucket_cnt  = (int*)(ws + off);            off += (size_t)NBUCK * 4;
    unsigned* bucket_buf = (unsigned*)(ws + off);     off += (size_t)NBUCK * BCAP * 4;
    (void)ws_size; (void)in_sizes; (void)n_in; (void)out_size;

    // ---- build CSR (grouped by dst) once: two-phase bucket sort ----
    hipMemsetAsync(bucket_cnt, 0, (size_t)NBUCK * sizeof(int), stream);
    bucket_scatter<<<(NE + 255) / 256, 256, 0, stream>>>(ei, bucket_cnt, bucket_buf);
    bucket_hist<<<NBUCK, 256, 0, stream>>>(bucket_cnt, bucket_buf, counts);
    scan1<<<SCAN_NB, SCAN_T, 0, stream>>>(counts, offsets, blocksums);
    scan2<<<1, 128, 0, stream>>>(blocksums);
    scan3<<<(NN + 255) / 256, 256, 0, stream>>>(offsets, blocksums);
    csr_write<<<NBUCK, 256, 0, stream>>>(bucket_cnt, bucket_buf, offsets, sorted_src);

    run_layer<8,  64, true >(x,  Wb0, offsets, sorted_src, q, kv, h0,  stream);
    run_layer<64, 64, true >(h0, Wb1, offsets, sorted_src, q, kv, h1,  stream);
    run_layer<64, 112, false>(h1, Wb2, offsets, sorted_src, q, kv, out, stream);
}

// Round 9
// 621.669 us; speedup vs baseline: 1.8648x; 1.8648x over previous
//
#include <hip/hip_runtime.h>
#include <hip/hip_fp16.h>
#include <math.h>
#include <float.h>

#define NN 100000
#define NE 1600000

#define SCAN_T 256
#define SCAN_E 1024
#define SCAN_NB ((NN + SCAN_E - 1) / SCAN_E)   // 98

#define NBUCK ((NN + 255) / 256)               // 391 buckets of 256 dsts
#define EPB   4096                             // edges per binning block
#define NBLK  ((NE + EPB - 1) / EPB)           // 391 binning blocks
#define HISTN (NBUCK * NBLK)                   // 152,881
#define GS_NB ((HISTN + SCAN_E - 1) / SCAN_E)  // 150
#define BCAP  5120                             // per-bucket LDS sort capacity

// ---------------- fused linear: q,skip fp32; k,v packed fp16 (R6 verbatim) ----------------
template<int IN, int OUT, int NPT, int NWIN>
__global__ __launch_bounds__(256)
void linear_qkvs(const float* __restrict__ x,
                 const float* __restrict__ Wq, const float* __restrict__ bq,
                 const float* __restrict__ Wk, const float* __restrict__ bk,
                 const float* __restrict__ Wv, const float* __restrict__ bv,
                 const float* __restrict__ Ws, const float* __restrict__ bs,
                 float* __restrict__ q, unsigned short* __restrict__ kv,
                 float* __restrict__ outskip) {
    const int t    = threadIdx.x;
    const int lane = t & 63;
    const int wv   = t >> 6;
    const int wid  = blockIdx.y * 4 + wv;        // [0, 4*NWIN)
    const int mat  = wid / NWIN;                 // 0..3 (wave-uniform)
    const int win  = wid % NWIN;
    const int c    = win * 64 + lane;
    const bool act = (c < OUT);
    const int cl   = act ? c : (OUT - 1);

    const float* W = (mat == 0) ? Wq : (mat == 1) ? Wk : (mat == 2) ? Wv : Ws;
    const float* B = (mat == 0) ? bq : (mat == 1) ? bk : (mat == 2) ? bv : bs;

    const int node0 = blockIdx.x * NPT;
    const float* xrow = x + (size_t)node0 * IN;

    float acc[NPT];
    float bias = B[cl];
#pragma unroll
    for (int p = 0; p < NPT; ++p) acc[p] = bias;

    for (int i0 = 0; i0 < IN; i0 += 4) {
        float w0 = W[(size_t)(i0 + 0) * OUT + cl];
        float w1 = W[(size_t)(i0 + 1) * OUT + cl];
        float w2 = W[(size_t)(i0 + 2) * OUT + cl];
        float w3 = W[(size_t)(i0 + 3) * OUT + cl];
#pragma unroll
        for (int p = 0; p < NPT; ++p) {
            float4 xv = *(const float4*)(xrow + p * IN + i0);  // wave-uniform
            acc[p] += xv.x * w0 + xv.y * w1 + xv.z * w2 + xv.w * w3;
        }
    }

    if (mat == 0) {
        if (act) {
#pragma unroll
            for (int p = 0; p < NPT; ++p)
                q[(size_t)(node0 + p) * OUT + c] = acc[p];
        }
    } else if (mat == 3) {
        if (act) {
#pragma unroll
            for (int p = 0; p < NPT; ++p)
                outskip[(size_t)(node0 + p) * OUT + c] = acc[p];
        }
    } else {
        const int base = (mat == 1) ? 0 : OUT;   // k block then v block
#pragma unroll
        for (int p = 0; p < NPT; ++p) {
            float other = __shfl_xor(acc[p], 1); // all lanes participate
            if (act && !(lane & 1)) {
                unsigned lo  = __half_as_ushort(__float2half_rn(acc[p]));
                unsigned hiu = __half_as_ushort(__float2half_rn(other));
                *(unsigned*)(kv + (size_t)(node0 + p) * (2 * OUT) + base + c)
                    = lo | (hiu << 16);
            }
        }
    }
}

// ---------------- deterministic radix partition by dst>>8 (no global atomics) ----------------
// Pass A: per-chunk LDS histogram -> hist[bucket][chunk]
__global__ __launch_bounds__(256)
void bin_count(const int* __restrict__ ei, int* __restrict__ hist) {
    __shared__ int h[NBUCK];
    const int t = threadIdx.x;
    for (int i = t; i < NBUCK; i += 256) h[i] = 0;
    __syncthreads();
    int e0 = blockIdx.x * EPB;
    int e1 = e0 + EPB < NE ? e0 + EPB : NE;
    for (int i = e0 + t; i < e1; i += 256)
        atomicAdd(&h[ei[NE + i] >> 8], 1);
    __syncthreads();
    for (int i = t; i < NBUCK; i += 256)
        hist[(size_t)i * NBLK + blockIdx.x] = h[i];
}

// generic 3-stage exclusive scan over HISTN elements (1024/block)
__global__ __launch_bounds__(SCAN_T)
void gscan1(int* __restrict__ a, int* __restrict__ bsums) {
    __shared__ int lds[SCAN_T];
    int t = threadIdx.x;
    int base = blockIdx.x * SCAN_E + t * 4;
    int vals[4];
    int s = 0;
#pragma unroll
    for (int j = 0; j < 4; ++j) {
        int idx = base + j;
        vals[j] = (idx < HISTN) ? a[idx] : 0;
        s += vals[j];
    }
    lds[t] = s;
    __syncthreads();
    for (int off = 1; off < SCAN_T; off <<= 1) {
        int xx = (t >= off) ? lds[t - off] : 0;
        __syncthreads();
        lds[t] += xx;
        __syncthreads();
    }
    int run = (t > 0) ? lds[t - 1] : 0;
    if (t == SCAN_T - 1) bsums[blockIdx.x] = lds[t];
#pragma unroll
    for (int j = 0; j < 4; ++j) {
        int idx = base + j;
        if (idx < HISTN) a[idx] = run;
        run += vals[j];
    }
}

__global__ __launch_bounds__(256)
void gscan2(int* __restrict__ bsums) {
    __shared__ int lds[256];
    int t = threadIdx.x;
    lds[t] = (t < GS_NB) ? bsums[t] : 0;
    __syncthreads();
    for (int off = 1; off < 256; off <<= 1) {
        int xx = (t >= off) ? lds[t - off] : 0;
        __syncthreads();
        lds[t] += xx;
        __syncthreads();
    }
    if (t < GS_NB) bsums[t] = (t > 0) ? lds[t - 1] : 0;
}

__global__ __launch_bounds__(256)
void gscan3(int* __restrict__ a, const int* __restrict__ bsums,
            int* __restrict__ bstart) {
    int i = blockIdx.x * 256 + threadIdx.x;
    if (i < HISTN) {
        int v = a[i] + bsums[i / SCAN_E];
        a[i] = v;
        if (i % NBLK == 0) bstart[i / NBLK] = v;   // bucket start
    }
    if (i == 0) bstart[NBUCK] = NE;
}

// Pass C: scatter packed edges into compact per-bucket segments of ebuf.
// Each (bucket, chunk) cell exclusively owned -> LDS atomics only.
__global__ __launch_bounds__(256)
void bin_scatter(const int* __restrict__ ei, const int* __restrict__ hist,
                 unsigned* __restrict__ ebuf) {
    __shared__ int off[NBUCK];
    const int t = threadIdx.x;
    for (int i = t; i < NBUCK; i += 256)
        off[i] = hist[(size_t)i * NBLK + blockIdx.x];
    __syncthreads();
    int e0 = blockIdx.x * EPB;
    int e1 = e0 + EPB < NE ? e0 + EPB : NE;
    for (int i = e0 + t; i < e1; i += 256) {
        int src = ei[i];
        int dst = ei[NE + i];
        int b = dst >> 8;
        int p = atomicAdd(&off[b], 1);
        ebuf[p] = ((unsigned)(dst & 255) << 17) | (unsigned)src;
    }
}

// per-bucket LDS histogram -> per-dst counts
__global__ __launch_bounds__(256)
void bucket_hist(const int* __restrict__ bstart,
                 const unsigned* __restrict__ ebuf,
                 int* __restrict__ counts) {
    __shared__ int h[256];
    const int b = blockIdx.x;
    const int t = threadIdx.x;
    h[t] = 0;
    __syncthreads();
    int beg = bstart[b], end = bstart[b + 1];
    for (int i = beg + t; i < end; i += 256)
        atomicAdd(&h[ebuf[i] >> 17], 1);
    __syncthreads();
    int d = b * 256 + t;
    if (d < NN) counts[d] = h[t];
}

// ---- dst-level scan (offsets over NN) ----
__global__ __launch_bounds__(SCAN_T)
void scan1(const int* __restrict__ counts, int* __restrict__ offsets,
           int* __restrict__ blocksums) {
    __shared__ int lds[SCAN_T];
    int t = threadIdx.x;
    int base = blockIdx.x * SCAN_E + t * 4;
    int vals[4];
    int s = 0;
#pragma unroll
    for (int j = 0; j < 4; ++j) {
        int idx = base + j;
        vals[j] = (idx < NN) ? counts[idx] : 0;
        s += vals[j];
    }
    lds[t] = s;
    __syncthreads();
    for (int off = 1; off < SCAN_T; off <<= 1) {
        int xx = (t >= off) ? lds[t - off] : 0;
        __syncthreads();
        lds[t] += xx;
        __syncthreads();
    }
    int run = (t > 0) ? lds[t - 1] : 0;
    if (t == SCAN_T - 1) blocksums[blockIdx.x] = lds[t];
#pragma unroll
    for (int j = 0; j < 4; ++j) {
        int idx = base + j;
        if (idx < NN) offsets[idx] = run;
        run += vals[j];
    }
}

__global__ __launch_bounds__(128)
void scan2(int* __restrict__ blocksums) {
    __shared__ int lds[128];
    int t = threadIdx.x;
    lds[t] = (t < SCAN_NB) ? blocksums[t] : 0;
    __syncthreads();
    for (int off = 1; off < 128; off <<= 1) {
        int xx = (t >= off) ? lds[t - off] : 0;
        __syncthreads();
        lds[t] += xx;
        __syncthreads();
    }
    if (t < SCAN_NB) blocksums[t] = (t > 0) ? lds[t - 1] : 0;
}

__global__ __launch_bounds__(256)
void scan3(int* __restrict__ offsets, const int* __restrict__ blocksums) {
    int i = blockIdx.x * blockDim.x + threadIdx.x;
    if (i < NN) offsets[i] = offsets[i] + blocksums[i / SCAN_E];
    if (i == 0) offsets[NN] = NE;
}

// sort each bucket in LDS, write its (contiguous) CSR segment coalesced
__global__ __launch_bounds__(256)
void csr_write(const int* __restrict__ bstart,
               const unsigned* __restrict__ ebuf,
               const int* __restrict__ offsets,
               int* __restrict__ sorted_src) {
    __shared__ int h[256];
    __shared__ int pre[256];
    __shared__ int posi[256];
    __shared__ unsigned srt[BCAP];
    const int b = blockIdx.x;
    const int t = threadIdx.x;
    h[t] = 0;
    __syncthreads();
    int beg = bstart[b];
    int cnt = bstart[b + 1] - beg;
    cnt = cnt < BCAP ? cnt : BCAP;
    const unsigned* buf = ebuf + beg;
    for (int i = t; i < cnt; i += 256)
        atomicAdd(&h[buf[i] >> 17], 1);
    __syncthreads();
    int v = h[t];
    pre[t] = v;
    __syncthreads();
    for (int off = 1; off < 256; off <<= 1) {
        int xx = (t >= off) ? pre[t - off] : 0;
        __syncthreads();
        pre[t] += xx;
        __syncthreads();
    }
    posi[t] = pre[t] - v;   // exclusive
    __syncthreads();
    for (int i = t; i < cnt; i += 256) {
        unsigned u = buf[i];
        int dl = u >> 17;
        int p = atomicAdd(&posi[dl], 1);
        srt[p] = u & 0x1FFFFu;
    }
    __syncthreads();
    const int base = offsets[b << 8];
    for (int i = t; i < cnt; i += 256)
        sorted_src[base + i] = (int)srt[i];
}

// ---- 16-lane row sum via DPP rotates (VALU pipe, no LDS) ----
__device__ __forceinline__ float row16_sum(float x) {
    int y;
    y = __builtin_amdgcn_update_dpp(0, __float_as_int(x), 0x121, 0xF, 0xF, true); x += __int_as_float(y); // ror:1
    y = __builtin_amdgcn_update_dpp(0, __float_as_int(x), 0x122, 0xF, 0xF, true); x += __int_as_float(y); // ror:2
    y = __builtin_amdgcn_update_dpp(0, __float_as_int(x), 0x124, 0xF, 0xF, true); x += __int_as_float(y); // ror:4
    y = __builtin_amdgcn_update_dpp(0, __float_as_int(x), 0x128, 0xF, 0xF, true); x += __int_as_float(y); // ror:8
    return x;
}

__device__ __forceinline__ float4 h4_to_f4(uint2 w) {
    union { unsigned u; __half2 h; } a, b;
    a.u = w.x; b.u = w.y;
    float2 f0 = __half22float2(a.h);
    float2 f1 = __half22float2(b.h);
    return make_float4(f0.x, f0.y, f1.x, f1.y);
}

// ---------------- fused attention gather (R6 verbatim) ----------------
template<int C, bool RELU>
__global__ __launch_bounds__(256)
void attn_gather(const int* __restrict__ offsets,
                 const int* __restrict__ sorted_src,
                 const float* __restrict__ q,
                 const unsigned short* __restrict__ kv,
                 float* __restrict__ out, float scale) {
    const int wid  = (int)((blockIdx.x * blockDim.x + threadIdx.x) >> 6);
    const int lane = threadIdx.x & 63;
    if (wid >= NN) return;
    const int grp = lane >> 4;
    const int ch  = (lane & 15) * 4;
    constexpr bool P2 = (C > 64);
    const bool hi = P2 && (ch + 64 < C);

    const int beg = offsets[wid], end = offsets[wid + 1];

    float4 qv0 = *(const float4*)(q + (size_t)wid * C + ch);
    float4 qv1 = make_float4(0.f, 0.f, 0.f, 0.f);
    if (hi) qv1 = *(const float4*)(q + (size_t)wid * C + ch + 64);

    float m = -FLT_MAX, l = 0.f;
    float4 a0 = make_float4(0.f, 0.f, 0.f, 0.f);
    float4 a1 = make_float4(0.f, 0.f, 0.f, 0.f);

    int i = beg + grp;
    uint2 kw0 = make_uint2(0, 0), vw0 = kw0, kw1 = kw0, vw1 = kw0;
    if (i < end) {
        const unsigned short* row = kv + (size_t)sorted_src[i] * (2 * C);
        kw0 = *(const uint2*)(row + ch);
        vw0 = *(const uint2*)(row + C + ch);
        if (hi) {
            kw1 = *(const uint2*)(row + 64 + ch);
            vw1 = *(const uint2*)(row + C + 64 + ch);
        }
    }
    while (i < end) {
        int inext = i + 4;
        uint2 nkw0 = make_uint2(0, 0), nvw0 = nkw0, nkw1 = nkw0, nvw1 = nkw0;
        if (inext < end) {
            const unsigned short* row = kv + (size_t)sorted_src[inext] * (2 * C);
            nkw0 = *(const uint2*)(row + ch);
            nvw0 = *(const uint2*)(row + C + ch);
            if (hi) {
                nkw1 = *(const uint2*)(row + 64 + ch);
                nvw1 = *(const uint2*)(row + C + 64 + ch);
            }
        }
        float4 kf0 = h4_to_f4(kw0);
        float4 vf0 = h4_to_f4(vw0);
        float part = qv0.x * kf0.x + qv0.y * kf0.y + qv0.z * kf0.z + qv0.w * kf0.w;
        float4 kf1, vf1;
        if (P2) {
            kf1 = h4_to_f4(kw1);
            vf1 = h4_to_f4(vw1);
            part += qv1.x * kf1.x + qv1.y * kf1.y + qv1.z * kf1.z + qv1.w * kf1.w;
        }
        float s = row16_sum(part) * scale;
        float mn = fmaxf(m, s);
        float al = __expf(m - mn);
        float w  = __expf(s - mn);
        l = l * al + w;
        a0.x = a0.x * al + w * vf0.x; a0.y = a0.y * al + w * vf0.y;
        a0.z = a0.z * al + w * vf0.z; a0.w = a0.w * al + w * vf0.w;
        if (P2) {
            a1.x = a1.x * al + w * vf1.x; a1.y = a1.y * al + w * vf1.y;
            a1.z = a1.z * al + w * vf1.z; a1.w = a1.w * al + w * vf1.w;
        }
        m = mn;
        kw0 = nkw0; vw0 = nvw0; kw1 = nkw1; vw1 = nvw1;
        i = inext;
    }

    // merge the 4 groups: butterfly over lane-xor 16, 32
#pragma unroll
    for (int d = 16; d <= 32; d <<= 1) {
        float mo = __shfl_xor(m, d);
        float lo = __shfl_xor(l, d);
        float4 ao0, ao1;
        ao0.x = __shfl_xor(a0.x, d); ao0.y = __shfl_xor(a0.y, d);
        ao0.z = __shfl_xor(a0.z, d); ao0.w = __shfl_xor(a0.w, d);
        if (P2) {
            ao1.x = __shfl_xor(a1.x, d); ao1.y = __shfl_xor(a1.y, d);
            ao1.z = __shfl_xor(a1.z, d); ao1.w = __shfl_xor(a1.w, d);
        }
        float mn = fmaxf(m, mo);
        float e1 = (l  > 0.f) ? __expf(m  - mn) : 0.f;
        float e2 = (lo > 0.f) ? __expf(mo - mn) : 0.f;
        l = l * e1 + lo * e2;
        a0.x = a0.x * e1 + ao0.x * e2; a0.y = a0.y * e1 + ao0.y * e2;
        a0.z = a0.z * e1 + ao0.z * e2; a0.w = a0.w * e1 + ao0.w * e2;
        if (P2) {
            a1.x = a1.x * e1 + ao1.x * e2; a1.y = a1.y * e1 + ao1.y * e2;
            a1.z = a1.z * e1 + ao1.z * e2; a1.w = a1.w * e1 + ao1.w * e2;
        }
        m = mn;
    }

    if (lane < 16) {
        float inv = (l > 0.f) ? 1.f / l : 0.f;
        size_t o = (size_t)wid * C + ch;
        float4 sk = *(const float4*)(out + o);
        float4 r;
        r.x = sk.x + a0.x * inv; r.y = sk.y + a0.y * inv;
        r.z = sk.z + a0.z * inv; r.w = sk.w + a0.w * inv;
        if (RELU) {
            r.x = fmaxf(r.x, 0.f); r.y = fmaxf(r.y, 0.f);
            r.z = fmaxf(r.z, 0.f); r.w = fmaxf(r.w, 0.f);
        }
        *(float4*)(out + o) = r;
        if (hi) {
            float4 sk1 = *(const float4*)(out + o + 64);
            float4 r1;
            r1.x = sk1.x + a1.x * inv; r1.y = sk1.y + a1.y * inv;
            r1.z = sk1.z + a1.z * inv; r1.w = sk1.w + a1.w * inv;
            if (RELU) {
                r1.x = fmaxf(r1.x, 0.f); r1.y = fmaxf(r1.y, 0.f);
                r1.z = fmaxf(r1.z, 0.f); r1.w = fmaxf(r1.w, 0.f);
            }
            *(float4*)(out + o + 64) = r1;
        }
    }
}

// ---------------- host side ----------------
template<int IN, int OUT, bool RELU>
static void run_layer(const float* xin, const float* const* Wb,
                      const int* offsets, const int* sorted_src,
                      float* q, unsigned short* kv,
                      float* out, hipStream_t stream) {
    constexpr int NPT  = 16;                    // NN = 6250 * 16 exactly
    constexpr int NWIN = (OUT + 63) / 64;
    dim3 gl(NN / NPT, NWIN);
    linear_qkvs<IN, OUT, NPT, NWIN><<<gl, 256, 0, stream>>>(
        xin, Wb[0], Wb[1], Wb[2], Wb[3], Wb[4], Wb[5], Wb[6], Wb[7],
        q, kv, out);

    float scale = 1.0f / sqrtf((float)OUT);
    attn_gather<OUT, RELU><<<(NN + 3) / 4, 256, 0, stream>>>(
        offsets, sorted_src, q, kv, out, scale);
}

extern "C" void kernel_launch(void* const* d_in, const int* in_sizes, int n_in,
                              void* d_out, int out_size, void* d_ws, size_t ws_size,
                              hipStream_t stream) {
    const float* x  = (const float*)d_in[0];
    const int*   ei = (const int*)d_in[1];
    const float* Wb0[8], *Wb1[8], *Wb2[8];
    for (int i = 0; i < 8; ++i) {
        Wb0[i] = (const float*)d_in[2 + i];
        Wb1[i] = (const float*)d_in[10 + i];
        Wb2[i] = (const float*)d_in[18 + i];
    }
    float* out = (float*)d_out;

    char* ws = (char*)d_ws;
    const size_t CMAX = 112;
    size_t off = 0;
    float*          q  = (float*)(ws + off);          off += (size_t)NN * CMAX * 4;
    unsigned short* kv = (unsigned short*)(ws + off); off += (size_t)NN * 2 * CMAX * 2;
    float* h0          = (float*)(ws + off);          off += (size_t)NN * 64 * 4;
    float* h1          = (float*)(ws + off);          off += (size_t)NN * 64 * 4;
    int*   sorted_src  = (int*)(ws + off);            off += (size_t)NE * 4;
    int*   counts      = (int*)(ws + off);            off += (size_t)NN * 4;
    int*   offsets     = (int*)(ws + off);            off += (size_t)(NN + 1) * 4;
    int*   blocksums   = (int*)(ws + off);            off += (size_t)SCAN_NB * 4;
    int*   hist        = (int*)(ws + off);            off += (size_t)HISTN * 4;
    int*   gsums       = (int*)(ws + off);            off += (size_t)GS_NB * 4;
    int*   bstart      = (int*)(ws + off);            off += (size_t)(NBUCK + 1) * 4;
    unsigned* ebuf     = (unsigned*)(ws + off);       off += (size_t)NE * 4;
    (void)ws_size; (void)in_sizes; (void)n_in; (void)out_size;

    // ---- build CSR once: deterministic radix partition + per-bucket LDS sort ----
    bin_count<<<NBLK, 256, 0, stream>>>(ei, hist);
    gscan1<<<GS_NB, SCAN_T, 0, stream>>>(hist, gsums);
    gscan2<<<1, 256, 0, stream>>>(gsums);
    gscan3<<<(HISTN + 255) / 256, 256, 0, stream>>>(hist, gsums, bstart);
    bin_scatter<<<NBLK, 256, 0, stream>>>(ei, hist, ebuf);
    bucket_hist<<<NBUCK, 256, 0, stream>>>(bstart, ebuf, counts);
    scan1<<<SCAN_NB, SCAN_T, 0, stream>>>(counts, offsets, blocksums);
    scan2<<<1, 128, 0, stream>>>(blocksums);
    scan3<<<(NN + 255) / 256, 256, 0, stream>>>(offsets, blocksums);
    csr_write<<<NBUCK, 256, 0, stream>>>(bstart, ebuf, offsets, sorted_src);

    run_layer<8,  64, true >(x,  Wb0, offsets, sorted_src, q, kv, h0,  stream);
    run_layer<64, 64, true >(h0, Wb1, offsets, sorted_src, q, kv, h1,  stream);
    run_layer<64, 112, false>(h1, Wb2, offsets, sorted_src, q, kv, out, stream);
}